// Round 3
// baseline (522.711 us; speedup 1.0000x reference)
//
#include <hip/hip_runtime.h>
#include <hip/hip_bf16.h>
#include <stdint.h>

typedef unsigned short u16;
typedef __attribute__((ext_vector_type(8))) short bf16x8;   // 8 bf16 = 4 VGPRs
typedef __attribute__((ext_vector_type(4))) float f32x4;

#define B_SZ 4
#define T_SZ 2048
#define C_SZ 1024
#define NH   16
#define HD   64
#define NEG_BIG (-1.0e30f)

__device__ __forceinline__ u16 f2bf(float f) {
  unsigned int u = __float_as_uint(f);
  u += 0x7fffu + ((u >> 16) & 1u);   // RNE
  return (u16)(u >> 16);
}

// fp32 -> bf16 cast, 8 elements/thread
__global__ void cast_f32_bf16(const float* __restrict__ in, u16* __restrict__ out, int n8) {
  int i = blockIdx.x * blockDim.x + threadIdx.x;
  if (i < n8) {
    const float4* p = (const float4*)in + (size_t)i * 2;
    float4 a = p[0], b = p[1];
    bf16x8 o;
    o[0] = (short)f2bf(a.x); o[1] = (short)f2bf(a.y);
    o[2] = (short)f2bf(a.z); o[3] = (short)f2bf(a.w);
    o[4] = (short)f2bf(b.x); o[5] = (short)f2bf(b.y);
    o[6] = (short)f2bf(b.z); o[7] = (short)f2bf(b.w);
    ((bf16x8*)out)[i] = o;
  }
}

// C[M,N] = A[M,K](bf16) * Bw[N,K](bf16)^T + bias[N](fp32); out bf16 or fp32.
// m92-style staging (explicit vector load -> LDS store).
template <bool F32OUT>
__launch_bounds__(256, 2)
__global__ void gemm_bt(const u16* __restrict__ A, const u16* __restrict__ Bw,
                        const float* __restrict__ bias, void* __restrict__ Cout,
                        int M, int N, int K) {
  __shared__ __align__(16) u16 As[128 * 32];
  __shared__ __align__(16) u16 Bs[128 * 32];
  const int tid = threadIdx.x;
  const int lane = tid & 63;
  const int w = tid >> 6;
  const int wr = w >> 1, wc = w & 1;
  const int quad = lane >> 4, l16 = lane & 15;
  const int m0 = blockIdx.y * 128;
  const int n0 = blockIdx.x * 128;

  f32x4 acc[4][4];
#pragma unroll
  for (int i = 0; i < 4; i++)
#pragma unroll
    for (int j = 0; j < 4; j++) acc[i][j] = (f32x4){0.f, 0.f, 0.f, 0.f};

  for (int k0 = 0; k0 < K; k0 += 32) {
    __syncthreads();
#pragma unroll
    for (int i = 0; i < 2; i++) {
      const int c = tid + i * 256;
      const int r = c >> 2;            // 0..127
      const int cl = (c & 3) * 8;      // 0,8,16,24
      *(bf16x8*)&As[r * 32 + cl] = *(const bf16x8*)&A[(size_t)(m0 + r) * K + k0 + cl];
      *(bf16x8*)&Bs[r * 32 + cl] = *(const bf16x8*)&Bw[(size_t)(n0 + r) * K + k0 + cl];
    }
    __syncthreads();
    bf16x8 af[4], bfr[4];
#pragma unroll
    for (int mt = 0; mt < 4; mt++)
      af[mt] = *(const bf16x8*)&As[(wr * 64 + mt * 16 + l16) * 32 + quad * 8];
#pragma unroll
    for (int nt = 0; nt < 4; nt++)
      bfr[nt] = *(const bf16x8*)&Bs[(wc * 64 + nt * 16 + l16) * 32 + quad * 8];
#pragma unroll
    for (int mt = 0; mt < 4; mt++)
#pragma unroll
      for (int nt = 0; nt < 4; nt++)
        acc[mt][nt] = __builtin_amdgcn_mfma_f32_16x16x32_bf16(af[mt], bfr[nt], acc[mt][nt], 0, 0, 0);
  }

  float bv[4];
#pragma unroll
  for (int nt = 0; nt < 4; nt++) bv[nt] = bias[n0 + wc * 64 + nt * 16 + l16];

#pragma unroll
  for (int mt = 0; mt < 4; mt++) {
    const int row = m0 + wr * 64 + mt * 16 + quad * 4;   // C/D: row = quad*4+reg
#pragma unroll
    for (int nt = 0; nt < 4; nt++) {
      const int col = n0 + wc * 64 + nt * 16 + l16;      // C/D: col = lane&15
#pragma unroll
      for (int r = 0; r < 4; r++) {
        const float v = acc[mt][nt][r] + bv[nt];
        if (F32OUT)
          ((float*)Cout)[(size_t)(row + r) * N + col] = v;
        else
          ((u16*)Cout)[(size_t)(row + r) * N + col] = f2bf(v);
      }
    }
  }
}

// Flash attention: one block per (b, h, 64-row Q block). 4 waves, each owns 16 Q rows.
// No inf arithmetic: masks/init use -1e30f. bf16 in (qkv buffer), bf16 out.
__launch_bounds__(256, 2)
__global__ void attn_fused(const u16* __restrict__ qkv, u16* __restrict__ out) {
  __shared__ __align__(16) u16 Ks[64 * 72];
  __shared__ __align__(16) u16 Vt[64 * 72];
  __shared__ __align__(16) u16 Ps[4][16 * 72];
  const int qb = blockIdx.x, h = blockIdx.y, b = blockIdx.z;
  const int tid = threadIdx.x;
  const int lane = tid & 63, w = tid >> 6;
  const int quad = lane >> 4, l16 = lane & 15;
  const int t0 = qb * 64;
  const size_t RS = 3 * C_SZ;
  const size_t base = (size_t)b * T_SZ * RS + (size_t)h * HD;

  // Q fragments pinned in registers (A-operand layout: m=lane&15, k=quad*8+j)
  bf16x8 qf0, qf1;
  {
    const u16* qrow = qkv + base + (size_t)(t0 + w * 16 + l16) * RS;
    qf0 = *(const bf16x8*)(qrow + quad * 8);
    qf1 = *(const bf16x8*)(qrow + 32 + quad * 8);
  }

  f32x4 o[4];
#pragma unroll
  for (int i = 0; i < 4; i++) o[i] = (f32x4){0.f, 0.f, 0.f, 0.f};
  float m_i[4], l_i[4];
#pragma unroll
  for (int r = 0; r < 4; r++) { m_i[r] = NEG_BIG; l_i[r] = 0.f; }

  for (int kb = 0; kb <= qb; kb++) {
    const int kt0 = kb * 64;
    __syncthreads();   // protect Ks/Vt still being read last iter
#pragma unroll
    for (int i = 0; i < 2; i++) {
      const int c = tid + i * 256;       // 512 chunks of 8 elements
      const int kr = c >> 3;             // key row 0..63
      const int d0 = (c & 7) * 8;        // dim 0..56
      *(bf16x8*)&Ks[kr * 72 + d0] =
          *(const bf16x8*)(qkv + base + C_SZ + (size_t)(kt0 + kr) * RS + d0);
      bf16x8 vv = *(const bf16x8*)(qkv + base + 2 * C_SZ + (size_t)(kt0 + kr) * RS + d0);
#pragma unroll
      for (int j = 0; j < 8; j++) Vt[(d0 + j) * 72 + kr] = (u16)vv[j];
    }
    __syncthreads();

    // S = Q K^T  (16 q-rows x 64 k-cols per wave)
    f32x4 s[4];
#pragma unroll
    for (int nt = 0; nt < 4; nt++) {
      bf16x8 kf0 = *(const bf16x8*)&Ks[(nt * 16 + l16) * 72 + quad * 8];
      bf16x8 kf1 = *(const bf16x8*)&Ks[(nt * 16 + l16) * 72 + 32 + quad * 8];
      f32x4 t = (f32x4){0.f, 0.f, 0.f, 0.f};
      t = __builtin_amdgcn_mfma_f32_16x16x32_bf16(qf0, kf0, t, 0, 0, 0);
      t = __builtin_amdgcn_mfma_f32_16x16x32_bf16(qf1, kf1, t, 0, 0, 0);
      s[nt] = t;
    }

    // scale + causal mask (only diagonal block)
    const int qr0 = w * 16 + quad * 4;
#pragma unroll
    for (int nt = 0; nt < 4; nt++) {
      const int kc = nt * 16 + l16;
#pragma unroll
      for (int r = 0; r < 4; r++) {
        float v = s[nt][r] * 0.125f;
        if (kb == qb && kc > qr0 + r) v = NEG_BIG;
        s[nt][r] = v;
      }
    }

    // online softmax: row reductions over the 16 lanes of each quad-group
    float mnew[4], alpha[4];
#pragma unroll
    for (int r = 0; r < 4; r++) {
      float v = fmaxf(fmaxf(s[0][r], s[1][r]), fmaxf(s[2][r], s[3][r]));
      v = fmaxf(v, __shfl_xor(v, 1));
      v = fmaxf(v, __shfl_xor(v, 2));
      v = fmaxf(v, __shfl_xor(v, 4));
      v = fmaxf(v, __shfl_xor(v, 8));
      mnew[r] = fmaxf(m_i[r], v);
      alpha[r] = __expf(m_i[r] - mnew[r]);
      m_i[r] = mnew[r];
    }
    float rs[4] = {0.f, 0.f, 0.f, 0.f};
#pragma unroll
    for (int nt = 0; nt < 4; nt++)
#pragma unroll
      for (int r = 0; r < 4; r++) {
        float p = __expf(s[nt][r] - mnew[r]);
        s[nt][r] = p;
        rs[r] += p;
      }
#pragma unroll
    for (int r = 0; r < 4; r++) {
      float v = rs[r];
      v += __shfl_xor(v, 1);
      v += __shfl_xor(v, 2);
      v += __shfl_xor(v, 4);
      v += __shfl_xor(v, 8);
      l_i[r] = l_i[r] * alpha[r] + v;
#pragma unroll
      for (int nt = 0; nt < 4; nt++) o[nt][r] *= alpha[r];
    }

    // P: C/D layout -> LDS (padded) -> A-operand layout
#pragma unroll
    for (int nt = 0; nt < 4; nt++)
#pragma unroll
      for (int r = 0; r < 4; r++)
        Ps[w][(quad * 4 + r) * 72 + nt * 16 + l16] = f2bf(s[nt][r]);
    __syncthreads();
    bf16x8 p0 = *(const bf16x8*)&Ps[w][l16 * 72 + quad * 8];
    bf16x8 p1 = *(const bf16x8*)&Ps[w][l16 * 72 + 32 + quad * 8];
#pragma unroll
    for (int nt = 0; nt < 4; nt++) {
      bf16x8 v0 = *(const bf16x8*)&Vt[(nt * 16 + l16) * 72 + quad * 8];
      bf16x8 v1 = *(const bf16x8*)&Vt[(nt * 16 + l16) * 72 + 32 + quad * 8];
      o[nt] = __builtin_amdgcn_mfma_f32_16x16x32_bf16(p0, v0, o[nt], 0, 0, 0);
      o[nt] = __builtin_amdgcn_mfma_f32_16x16x32_bf16(p1, v1, o[nt], 0, 0, 0);
    }
  }

  // epilogue: O /= l, write [B,T,C] with head h at cols h*64..h*64+63
#pragma unroll
  for (int r = 0; r < 4; r++) {
    const float inv = (l_i[r] > 0.f) ? (1.f / l_i[r]) : 0.f;
    const size_t orow = ((size_t)b * T_SZ + t0 + w * 16 + quad * 4 + r) * C_SZ + (size_t)h * HD;
#pragma unroll
    for (int nt = 0; nt < 4; nt++)
      out[orow + nt * 16 + l16] = f2bf(o[nt][r] * inv);
  }
}

extern "C" void kernel_launch(void* const* d_in, const int* in_sizes, int n_in,
                              void* d_out, int out_size, void* d_ws, size_t ws_size,
                              hipStream_t stream) {
  (void)in_sizes; (void)n_in; (void)out_size; (void)ws_size;
  // fp32 inputs, per the reference file's dtypes
  const float* x      = (const float*)d_in[0];   // [B,T,C]
  const float* W_attn = (const float*)d_in[1];   // [3C,C]
  const float* b_attn = (const float*)d_in[2];   // [3C]
  const float* W_proj = (const float*)d_in[3];   // [C,C]
  const float* b_proj = (const float*)d_in[4];   // [C]
  float* out = (float*)d_out;                    // [B,T,C] fp32

  // workspace layout (bf16 buffers)
  char* ws = (char*)d_ws;
  u16* xb   = (u16*)ws;                                   ws += (size_t)8192 * 1024 * 2;  // 16 MB
  u16* Wab  = (u16*)ws;                                   ws += (size_t)3072 * 1024 * 2;  //  6 MB
  u16* Wpb  = (u16*)ws;                                   ws += (size_t)1024 * 1024 * 2;  //  2 MB
  u16* qkvb = (u16*)ws;                                   ws += (size_t)8192 * 3072 * 2;  // 48 MB
  u16* aob  = (u16*)ws;                                                                   // 16 MB

  dim3 blk(256);
  // casts: fp32 -> bf16
  cast_f32_bf16<<<(8192 * 1024 / 8 + 255) / 256, blk, 0, stream>>>(x, xb, 8192 * 1024 / 8);
  cast_f32_bf16<<<(3072 * 1024 / 8 + 255) / 256, blk, 0, stream>>>(W_attn, Wab, 3072 * 1024 / 8);
  cast_f32_bf16<<<(1024 * 1024 / 8 + 255) / 256, blk, 0, stream>>>(W_proj, Wpb, 1024 * 1024 / 8);

  // qkv = x @ W_attn^T + b_attn   (M=8192, N=3072, K=1024), bf16 out
  gemm_bt<false><<<dim3(3072 / 128, 8192 / 128), blk, 0, stream>>>(xb, Wab, b_attn, qkvb, 8192, 3072, 1024);
  // flash attention per (qblock, head, batch), bf16 out
  attn_fused<<<dim3(T_SZ / 64, NH, B_SZ), blk, 0, stream>>>(qkvb, aob);
  // y = att_out @ W_proj^T + b_proj  (M=8192, N=1024, K=1024), fp32 out
  gemm_bt<true><<<dim3(1024 / 128, 8192 / 128), blk, 0, stream>>>(aob, Wpb, b_proj, out, 8192, 1024, 1024);
}

// Round 4
// 430.329 us; speedup vs baseline: 1.2147x; 1.2147x over previous
//
#include <hip/hip_runtime.h>
#include <hip/hip_bf16.h>
#include <stdint.h>

typedef unsigned short u16;
typedef __attribute__((ext_vector_type(8))) short bf16x8;   // 8 bf16 = 4 VGPRs
typedef __attribute__((ext_vector_type(4))) short s16x4;    // 4 bf16 = 8B
typedef __attribute__((ext_vector_type(4))) float f32x4;

#define B_SZ 4
#define T_SZ 2048
#define C_SZ 1024
#define NH   16
#define HD   64
#define NEG_BIG (-1.0e30f)
#define LOG2E 1.44269504088896340736f

__device__ __forceinline__ u16 f2bf(float f) {        // RNE
  unsigned int u = __float_as_uint(f);
  u += 0x7fffu + ((u >> 16) & 1u);
  return (u16)(u >> 16);
}
__device__ __forceinline__ u16 f2bf_hu(float f) {     // round-half-up (2 ops)
  return (u16)((__float_as_uint(f) + 0x8000u) >> 16);
}
__device__ __forceinline__ void gload_lds16(const u16* g, u16* l) {
  __builtin_amdgcn_global_load_lds((const __attribute__((address_space(1))) void*)g,
                                   (__attribute__((address_space(3))) void*)l, 16, 0, 0);
}

// fp32 -> bf16 cast, 8 elements/thread
__global__ void cast_f32_bf16(const float* __restrict__ in, u16* __restrict__ out, int n8) {
  int i = blockIdx.x * blockDim.x + threadIdx.x;
  if (i < n8) {
    const float4* p = (const float4*)in + (size_t)i * 2;
    float4 a = p[0], b = p[1];
    bf16x8 o;
    o[0] = (short)f2bf(a.x); o[1] = (short)f2bf(a.y);
    o[2] = (short)f2bf(a.z); o[3] = (short)f2bf(a.w);
    o[4] = (short)f2bf(b.x); o[5] = (short)f2bf(b.y);
    o[6] = (short)f2bf(b.z); o[7] = (short)f2bf(b.w);
    ((bf16x8*)out)[i] = o;
  }
}

// C[M,N] = A[M,K](bf16) * Bw[N,K](bf16)^T + bias[N](fp32).
// m97 structure: 128x128 tile, BK=32, global_load_lds width-16 staging.
// MODE 0: fp32 row-major out (O0).
// MODE 1: QKV head-split epilogue: O0=qh[B,H,T,64], O1=kh[B,H,T,64], O2=vth[B,H,64,T] (bf16).
template <int MODE>
__launch_bounds__(256, 2)
__global__ void gemm_bt(const u16* __restrict__ A, const u16* __restrict__ Bw,
                        const float* __restrict__ bias,
                        void* __restrict__ O0, void* __restrict__ O1, void* __restrict__ O2,
                        int M, int N, int K) {
  __shared__ __align__(16) u16 As[128 * 32];
  __shared__ __align__(16) u16 Bs[128 * 32];
  const int tid = threadIdx.x;
  const int lane = tid & 63;
  const int w = tid >> 6;
  const int wr = w >> 1, wc = w & 1;
  const int quad = lane >> 4, l16 = lane & 15;
  const int m0 = blockIdx.y * 128;
  const int n0 = blockIdx.x * 128;

  // DMA staging: wave w stages rows [w*32, w*32+32); lane -> (row=lane>>2, col=(lane&3)*8)
  const int srow = lane >> 2;
  const int scol = (lane & 3) * 8;
  const u16* gA = A + (size_t)(m0 + w * 32 + srow) * K + scol;
  const u16* gB = Bw + (size_t)(n0 + w * 32 + srow) * K + scol;
  u16* lA0 = &As[(w * 32) * 32];
  u16* lA1 = &As[(w * 32 + 16) * 32];
  u16* lB0 = &Bs[(w * 32) * 32];
  u16* lB1 = &Bs[(w * 32 + 16) * 32];
  const size_t rstep = (size_t)16 * K;

  f32x4 acc[4][4];
#pragma unroll
  for (int i = 0; i < 4; i++)
#pragma unroll
    for (int j = 0; j < 4; j++) acc[i][j] = (f32x4){0.f, 0.f, 0.f, 0.f};

  for (int k0 = 0; k0 < K; k0 += 32) {
    __syncthreads();
    gload_lds16(gA + k0, lA0);
    gload_lds16(gA + rstep + k0, lA1);
    gload_lds16(gB + k0, lB0);
    gload_lds16(gB + rstep + k0, lB1);
    __syncthreads();   // compiler drains vmcnt before s_barrier
    bf16x8 af[4], bfr[4];
#pragma unroll
    for (int mt = 0; mt < 4; mt++)
      af[mt] = *(const bf16x8*)&As[(wr * 64 + mt * 16 + l16) * 32 + quad * 8];
#pragma unroll
    for (int nt = 0; nt < 4; nt++)
      bfr[nt] = *(const bf16x8*)&Bs[(wc * 64 + nt * 16 + l16) * 32 + quad * 8];
#pragma unroll
    for (int mt = 0; mt < 4; mt++)
#pragma unroll
      for (int nt = 0; nt < 4; nt++)
        acc[mt][nt] = __builtin_amdgcn_mfma_f32_16x16x32_bf16(af[mt], bfr[nt], acc[mt][nt], 0, 0, 0);
  }

  float bv[4];
#pragma unroll
  for (int nt = 0; nt < 4; nt++) bv[nt] = bias[n0 + wc * 64 + nt * 16 + l16];

  if (MODE == 0) {
    float* Cout = (float*)O0;
#pragma unroll
    for (int mt = 0; mt < 4; mt++) {
      const int row = m0 + wr * 64 + mt * 16 + quad * 4;   // C/D: row = quad*4+reg
#pragma unroll
      for (int nt = 0; nt < 4; nt++) {
        const int col = n0 + wc * 64 + nt * 16 + l16;      // C/D: col = lane&15
#pragma unroll
        for (int r = 0; r < 4; r++)
          Cout[(size_t)(row + r) * N + col] = acc[mt][nt][r] + bv[nt];
      }
    }
  } else {
    // head-split epilogue. Section (Q/K/V) and head are uniform per (block, wc):
    const int nsec = (n0 + wc * 64) >> 10;        // 0=Q,1=K,2=V (tile never crosses)
    const int hh = ((n0 + wc * 64) >> 6) & 15;    // head
    if (nsec < 2) {
      u16* dst = (u16*)(nsec == 0 ? O0 : O1);     // [B,H,T,64]
#pragma unroll
      for (int mt = 0; mt < 4; mt++) {
        const int row = m0 + wr * 64 + mt * 16 + quad * 4;
        const int bb = row >> 11;
        const int t = row & 2047;
#pragma unroll
        for (int nt = 0; nt < 4; nt++) {
          const int dh = nt * 16 + l16;
          const size_t a = (((size_t)bb * NH + hh) * T_SZ + t) * HD + dh;
#pragma unroll
          for (int r = 0; r < 4; r++)
            dst[a + (size_t)r * HD] = f2bf(acc[mt][nt][r] + bv[nt]);
        }
      }
    } else {
      u16* vth = (u16*)O2;                        // [B,H,64,T] (transposed)
#pragma unroll
      for (int mt = 0; mt < 4; mt++) {
        const int row = m0 + wr * 64 + mt * 16 + quad * 4;
        const int bb = row >> 11;
        const int t = row & 2047;                 // r adds 0..3, same batch
#pragma unroll
        for (int nt = 0; nt < 4; nt++) {
          const int dh = nt * 16 + l16;
          s16x4 pk;
#pragma unroll
          for (int r = 0; r < 4; r++) pk[r] = (short)f2bf(acc[mt][nt][r] + bv[nt]);
          *(s16x4*)&vth[(((size_t)bb * NH + hh) * HD + dh) * T_SZ + t] = pk;  // 8B store
        }
      }
    }
  }
}

// Flash attention v2: block = (qb 128 rows, h, b); 4 waves x 32 q-rows (2 m-frags).
// K from kh[B,H,T,64] (contiguous 8KB tiles), V from vth[B,H,64,T] (contiguous rows).
// Ps is wave-private (no barrier); 2 barriers per kb-iter; exp2 softmax.
__launch_bounds__(256, 4)
__global__ void attn_fused(const u16* __restrict__ qh, const u16* __restrict__ kh,
                           const u16* __restrict__ vth, u16* __restrict__ out) {
  __shared__ __align__(16) u16 Ks[64 * 72];      // [t][d] stride 72
  __shared__ __align__(16) u16 Vs[64 * 72];      // [d][t] stride 72
  __shared__ __align__(16) u16 Ps[4][16 * 72];   // per-wave P strip [q][t]
  const int qb = 15 - blockIdx.x;                // big blocks dispatch first
  const int h = blockIdx.y, b = blockIdx.z;
  const int tid = threadIdx.x;
  const int lane = tid & 63, w = tid >> 6;
  const int quad = lane >> 4, l16 = lane & 15;
  const size_t bh = (size_t)b * NH + h;
  const u16* Kbase = kh + bh * T_SZ * HD;
  const u16* Vbase = vth + bh * HD * T_SZ;

  // Q fragments (A-layout: m=lane&15, k=quad*8+j), pinned for the kernel
  bf16x8 qf[2][2];
#pragma unroll
  for (int m = 0; m < 2; m++) {
    const int t = qb * 128 + w * 32 + m * 16 + l16;
    const u16* qrow = qh + (bh * T_SZ + t) * HD;
    qf[m][0] = *(const bf16x8*)(qrow + quad * 8);
    qf[m][1] = *(const bf16x8*)(qrow + 32 + quad * 8);
  }

  f32x4 o[2][4];
  float m_i[2][4], l_i[2][4];
#pragma unroll
  for (int m = 0; m < 2; m++)
#pragma unroll
    for (int i = 0; i < 4; i++) {
      o[m][i] = (f32x4){0.f, 0.f, 0.f, 0.f};
      m_i[m][i] = NEG_BIG; l_i[m][i] = 0.f;
    }

  const int kbn = 2 * qb + 2;
  for (int kb = 0; kb < kbn; kb++) {
    const int kt0 = kb * 64;
    __syncthreads();   // all waves done reading Ks/Vs of prev iter
#pragma unroll
    for (int i = 0; i < 2; i++) {
      const int c = tid + i * 256;       // 512 chunks of 16B
      const int r = c >> 3;              // row 0..63
      const int c8 = (c & 7) * 8;        // col 0..56
      *(bf16x8*)&Ks[r * 72 + c8] = *(const bf16x8*)(Kbase + (size_t)(kt0 + r) * HD + c8);
      *(bf16x8*)&Vs[r * 72 + c8] = *(const bf16x8*)(Vbase + (size_t)r * T_SZ + kt0 + c8);
    }
    __syncthreads();

#pragma unroll
    for (int m = 0; m < 2; m++) {
      const int qr = qb * 128 + w * 32 + m * 16 + quad * 4;   // + r
      const bool diag = (kt0 + 64 > qb * 128 + w * 32 + m * 16);  // wave-uniform

      // S = Q K^T
      f32x4 s[4];
#pragma unroll
      for (int nt = 0; nt < 4; nt++) {
        bf16x8 kf0 = *(const bf16x8*)&Ks[(nt * 16 + l16) * 72 + quad * 8];
        bf16x8 kf1 = *(const bf16x8*)&Ks[(nt * 16 + l16) * 72 + 32 + quad * 8];
        f32x4 t0 = (f32x4){0.f, 0.f, 0.f, 0.f};
        t0 = __builtin_amdgcn_mfma_f32_16x16x32_bf16(qf[m][0], kf0, t0, 0, 0, 0);
        t0 = __builtin_amdgcn_mfma_f32_16x16x32_bf16(qf[m][1], kf1, t0, 0, 0, 0);
        s[nt] = t0;
      }

      // scale into log2 domain + causal mask
      const float SC = 0.125f * LOG2E;
#pragma unroll
      for (int nt = 0; nt < 4; nt++) {
        const int kc = kt0 + nt * 16 + l16;
#pragma unroll
        for (int r = 0; r < 4; r++) {
          float v = s[nt][r] * SC;
          if (diag && kc > qr + r) v = NEG_BIG;
          s[nt][r] = v;
        }
      }

      // online softmax (base-2)
      float mnew[4], alpha[4];
#pragma unroll
      for (int r = 0; r < 4; r++) {
        float v = fmaxf(fmaxf(s[0][r], s[1][r]), fmaxf(s[2][r], s[3][r]));
        v = fmaxf(v, __shfl_xor(v, 1));
        v = fmaxf(v, __shfl_xor(v, 2));
        v = fmaxf(v, __shfl_xor(v, 4));
        v = fmaxf(v, __shfl_xor(v, 8));
        mnew[r] = fmaxf(m_i[m][r], v);
        alpha[r] = exp2f(m_i[m][r] - mnew[r]);
        m_i[m][r] = mnew[r];
      }
      float rs[4] = {0.f, 0.f, 0.f, 0.f};
#pragma unroll
      for (int nt = 0; nt < 4; nt++)
#pragma unroll
        for (int r = 0; r < 4; r++) {
          float p = exp2f(s[nt][r] - mnew[r]);
          s[nt][r] = p;
          rs[r] += p;
        }
#pragma unroll
      for (int r = 0; r < 4; r++) {
        float v = rs[r];
        v += __shfl_xor(v, 1);
        v += __shfl_xor(v, 2);
        v += __shfl_xor(v, 4);
        v += __shfl_xor(v, 8);
        l_i[m][r] = l_i[m][r] * alpha[r] + v;
#pragma unroll
        for (int nt = 0; nt < 4; nt++) o[m][nt][r] *= alpha[r];
      }

      // P: C/D -> wave-private LDS strip -> A-layout (lgkmcnt orders, no barrier)
#pragma unroll
      for (int nt = 0; nt < 4; nt++)
#pragma unroll
        for (int r = 0; r < 4; r++)
          Ps[w][(quad * 4 + r) * 72 + nt * 16 + l16] = f2bf_hu(s[nt][r]);
      bf16x8 p0 = *(const bf16x8*)&Ps[w][l16 * 72 + quad * 8];
      bf16x8 p1 = *(const bf16x8*)&Ps[w][l16 * 72 + 32 + quad * 8];
#pragma unroll
      for (int nt = 0; nt < 4; nt++) {
        bf16x8 v0 = *(const bf16x8*)&Vs[(nt * 16 + l16) * 72 + quad * 8];
        bf16x8 v1 = *(const bf16x8*)&Vs[(nt * 16 + l16) * 72 + 32 + quad * 8];
        o[m][nt] = __builtin_amdgcn_mfma_f32_16x16x32_bf16(p0, v0, o[m][nt], 0, 0, 0);
        o[m][nt] = __builtin_amdgcn_mfma_f32_16x16x32_bf16(p1, v1, o[m][nt], 0, 0, 0);
      }
    }
  }

  // epilogue: O /= l -> out[B,T,C] row-major bf16 (cols h*64..h*64+63)
#pragma unroll
  for (int m = 0; m < 2; m++)
#pragma unroll
    for (int r = 0; r < 4; r++) {
      const float inv = 1.f / l_i[m][r];
      const int t = qb * 128 + w * 32 + m * 16 + quad * 4 + r;
      const size_t orow = ((size_t)b * T_SZ + t) * C_SZ + (size_t)h * HD;
#pragma unroll
      for (int nt = 0; nt < 4; nt++)
        out[orow + nt * 16 + l16] = f2bf(o[m][nt][r] * inv);
    }
}

extern "C" void kernel_launch(void* const* d_in, const int* in_sizes, int n_in,
                              void* d_out, int out_size, void* d_ws, size_t ws_size,
                              hipStream_t stream) {
  (void)in_sizes; (void)n_in; (void)out_size; (void)ws_size;
  const float* x      = (const float*)d_in[0];   // [B,T,C]
  const float* W_attn = (const float*)d_in[1];   // [3C,C]
  const float* b_attn = (const float*)d_in[2];   // [3C]
  const float* W_proj = (const float*)d_in[3];   // [C,C]
  const float* b_proj = (const float*)d_in[4];   // [C]
  float* out = (float*)d_out;                    // [B,T,C] fp32

  char* ws = (char*)d_ws;
  u16* xb  = (u16*)ws;  ws += (size_t)8192 * 1024 * 2;   // 16 MB
  u16* Wab = (u16*)ws;  ws += (size_t)3072 * 1024 * 2;   //  6 MB
  u16* Wpb = (u16*)ws;  ws += (size_t)1024 * 1024 * 2;   //  2 MB
  u16* qhb = (u16*)ws;  ws += (size_t)8192 * 1024 * 2;   // 16 MB  [B,H,T,64]
  u16* khb = (u16*)ws;  ws += (size_t)8192 * 1024 * 2;   // 16 MB  [B,H,T,64]
  u16* vtb = (u16*)ws;  ws += (size_t)8192 * 1024 * 2;   // 16 MB  [B,H,64,T]
  u16* aob = (u16*)ws;                                   // 16 MB  [B,T,C]

  dim3 blk(256);
  cast_f32_bf16<<<(8192 * 1024 / 8 + 255) / 256, blk, 0, stream>>>(x, xb, 8192 * 1024 / 8);
  cast_f32_bf16<<<(3072 * 1024 / 8 + 255) / 256, blk, 0, stream>>>(W_attn, Wab, 3072 * 1024 / 8);
  cast_f32_bf16<<<(1024 * 1024 / 8 + 255) / 256, blk, 0, stream>>>(W_proj, Wpb, 1024 * 1024 / 8);

  // qkv = x @ W_attn^T + b_attn -> head-split qh/kh/vth
  gemm_bt<1><<<dim3(3072 / 128, 8192 / 128), blk, 0, stream>>>(
      xb, Wab, b_attn, qhb, khb, vtb, 8192, 3072, 1024);
  // flash attention
  attn_fused<<<dim3(T_SZ / 128, NH, B_SZ), blk, 0, stream>>>(qhb, khb, vtb, aob);
  // y = att @ W_proj^T + b_proj (fp32 out)
  gemm_bt<0><<<dim3(1024 / 128, 8192 / 128), blk, 0, stream>>>(
      aob, Wpb, b_proj, out, nullptr, nullptr, 8192, 1024, 1024);
}